// Round 1
// baseline (265.106 us; speedup 1.0000x reference)
//
#include <hip/hip_runtime.h>
#include <math.h>

typedef __fp16   fp16x2  __attribute__((ext_vector_type(2)));
typedef _Float16 half8   __attribute__((ext_vector_type(8)));
typedef float    floatx4 __attribute__((ext_vector_type(4)));

#define M_TOTAL 16384
#define K_DIM   2048
#define BM      32
#define BK      32
#define NT      256
#define NCHUNK  (K_DIM / BK)   // 64

__device__ __forceinline__ void gl_lds16(const _Float16* g, _Float16* l) {
    __builtin_amdgcn_global_load_lds((const __attribute__((address_space(1))) void*)g,
                                     (__attribute__((address_space(3))) void*)l, 16, 0, 0);
}

// Pre-convert W (router||noise, fp32 [128][2048]) into ws as hi/lo f16,
// granule-major per 32-k chunk: chunk c = 8192 halves:
//   hi: [(g*128 + col)*8 + j]  (g=0..3 k-granule, col=0..127, j=0..7)
//   lo: same at +4096 halves
__global__ __launch_bounds__(256) void conv_w_kernel(
    const float* __restrict__ rw, const float* __restrict__ nw,
    _Float16* __restrict__ wsB)
{
    const int u   = blockIdx.x * 256 + threadIdx.x;  // 0..32767
    const int col = u & 127;
    const int g   = (u >> 7) & 3;
    const int c   = u >> 9;
    const float* srcRow = (col < 64) ? (rw + (size_t)col * K_DIM)
                                     : (nw + (size_t)(col - 64) * K_DIM);
    const float* src = srcRow + c * BK + g * 8;
    const float4 v0 = *(const float4*)src;
    const float4 v1 = *(const float4*)(src + 4);
    union { fp16x2 h[4]; uint4 q; } ph, pl;
    ph.h[0] = __builtin_amdgcn_cvt_pkrtz(v0.x, v0.y);
    ph.h[1] = __builtin_amdgcn_cvt_pkrtz(v0.z, v0.w);
    ph.h[2] = __builtin_amdgcn_cvt_pkrtz(v1.x, v1.y);
    ph.h[3] = __builtin_amdgcn_cvt_pkrtz(v1.z, v1.w);
    pl.h[0] = __builtin_amdgcn_cvt_pkrtz((v0.x - (float)ph.h[0].x) * 2048.0f,
                                         (v0.y - (float)ph.h[0].y) * 2048.0f);
    pl.h[1] = __builtin_amdgcn_cvt_pkrtz((v0.z - (float)ph.h[1].x) * 2048.0f,
                                         (v0.w - (float)ph.h[1].y) * 2048.0f);
    pl.h[2] = __builtin_amdgcn_cvt_pkrtz((v1.x - (float)ph.h[2].x) * 2048.0f,
                                         (v1.y - (float)ph.h[2].y) * 2048.0f);
    pl.h[3] = __builtin_amdgcn_cvt_pkrtz((v1.z - (float)ph.h[3].x) * 2048.0f,
                                         (v1.w - (float)ph.h[3].y) * 2048.0f);
    const size_t base = (size_t)c * 8192 + ((size_t)g * 128 + col) * 8;
    *(uint4*)&wsB[base]        = ph.q;
    *(uint4*)&wsB[base + 4096] = pl.q;
}

// Barrier-free K-loop: each wave stages a PRIVATE copy of the 8 B-segments it
// consumes (8 KB/chunk), double-buffered, synced only by its own vmcnt.
// A fragments are loaded direct-to-register (2 chunks ahead) and converted
// to hi/lo f16 in registers -- A never touches LDS.
__global__ __launch_bounds__(NT, 2) void gemm_router_kernel(
    const float* __restrict__ x,
    const _Float16* __restrict__ wsB,
    const float* __restrict__ router_b,
    const float* __restrict__ noise_b,
    const float* __restrict__ noise_u,
    float* __restrict__ out)
{
    __shared__ __align__(16) union {
        _Float16 B[2][4][4096];   // [buf][wave][seg(hi g0..3, lo g0..3) * 512] = 64 KB
        struct { float Cs[32][132]; float p1[32]; float p2[32]; int i1[32]; int i2[32]; } e;
    } sm;

    const int t    = threadIdx.x;
    const int lane = t & 63;
    const int w    = t >> 6;
    const int rowBase = blockIdx.x * BM;

    // fragment map: wave w -> rows mt0..+16, cols nt0..+64
    const int lr  = lane & 15;
    const int lg4 = lane >> 4;
    const int mt0 = (w & 1) * 16;
    const int nt0 = (w >> 1) * 64;

    // A: lane's own fragment source: row mt0+lr, k = c*32 + lg4*8 .. +8
    const float* pa = x + (size_t)(rowBase + mt0 + lr) * K_DIM + lg4 * 8;
    // B: per-lane source for this wave's segments (add c*8192 + g*1024 (+4096 lo))
    const _Float16* wsrc = wsB + (size_t)nt0 * 8 + (size_t)lane * 8;

    _Float16* const b0 = &sm.B[0][w][0];
    _Float16* const b1 = &sm.B[1][w][0];

    // prologue: stage B(0), load A(0), A(1)  -> 12 vmem ops outstanding
    #pragma unroll
    for (int g = 0; g < 4; ++g) {
        gl_lds16(wsrc + g * 1024,        b0 + g * 512);
        gl_lds16(wsrc + 4096 + g * 1024, b0 + 2048 + g * 512);
    }
    float4 A0a = *(const float4*)(pa);
    float4 A0b = *(const float4*)(pa + 4);
    float4 A1a = *(const float4*)(pa + 32);
    float4 A1b = *(const float4*)(pa + 36);

    floatx4 acch[4], accx[4];
    #pragma unroll
    for (int ni = 0; ni < 4; ++ni) { acch[ni] = (floatx4)0.0f; accx[ni] = (floatx4)0.0f; }

    #pragma unroll 2
    for (int c = 0; c < NCHUNK; ++c) {
        _Float16* const cur = (c & 1) ? b1 : b0;
        _Float16* const nxt = (c & 1) ? b0 : b1;

        // issue B(c+1) (8 gl_lds) and A(c+2) (2 loads); indices clamped so the
        // issue count is uniform (10/iter) -> vmcnt(10) always correct.
        const int cn  = (c + 1 < NCHUNK) ? c + 1 : NCHUNK - 1;
        const int cn2 = (c + 2 < NCHUNK) ? c + 2 : NCHUNK - 1;
        const _Float16* wsn = wsrc + (size_t)cn * 8192;
        #pragma unroll
        for (int g = 0; g < 4; ++g) {
            gl_lds16(wsn + g * 1024,        nxt + g * 512);
            gl_lds16(wsn + 4096 + g * 1024, nxt + 2048 + g * 512);
        }
        const float4 A2a = *(const float4*)(pa + cn2 * 32);
        const float4 A2b = *(const float4*)(pa + cn2 * 32 + 4);

        // wait for all but the 10 ops just issued: B(c) staged, A(c)/A(c+1) resident
        asm volatile("s_waitcnt vmcnt(10)" ::: "memory");

        half8 bh[4], bl[4];
        #pragma unroll
        for (int ni = 0; ni < 4; ++ni) {
            const int co = lg4 * 512 + (ni * 16 + lr) * 8;
            bh[ni] = *(const half8*)&cur[co];
            bl[ni] = *(const half8*)&cur[2048 + co];
        }

        // convert A(c) fp32 -> hi/lo f16 fragments in registers
        union { fp16x2 h[4]; half8 v; } H, L;
        H.h[0] = __builtin_amdgcn_cvt_pkrtz(A0a.x, A0a.y);
        H.h[1] = __builtin_amdgcn_cvt_pkrtz(A0a.z, A0a.w);
        H.h[2] = __builtin_amdgcn_cvt_pkrtz(A0b.x, A0b.y);
        H.h[3] = __builtin_amdgcn_cvt_pkrtz(A0b.z, A0b.w);
        L.h[0] = __builtin_amdgcn_cvt_pkrtz((A0a.x - (float)H.h[0].x) * 2048.0f,
                                            (A0a.y - (float)H.h[0].y) * 2048.0f);
        L.h[1] = __builtin_amdgcn_cvt_pkrtz((A0a.z - (float)H.h[1].x) * 2048.0f,
                                            (A0a.w - (float)H.h[1].y) * 2048.0f);
        L.h[2] = __builtin_amdgcn_cvt_pkrtz((A0b.x - (float)H.h[2].x) * 2048.0f,
                                            (A0b.y - (float)H.h[2].y) * 2048.0f);
        L.h[3] = __builtin_amdgcn_cvt_pkrtz((A0b.z - (float)H.h[3].x) * 2048.0f,
                                            (A0b.w - (float)H.h[3].y) * 2048.0f);
        const half8 ah = H.v;
        const half8 al = L.v;

        __builtin_amdgcn_s_setprio(1);
        #pragma unroll
        for (int ni = 0; ni < 4; ++ni) {
            acch[ni] = __builtin_amdgcn_mfma_f32_16x16x32_f16(ah, bh[ni], acch[ni], 0, 0, 0);
            accx[ni] = __builtin_amdgcn_mfma_f32_16x16x32_f16(ah, bl[ni], accx[ni], 0, 0, 0);
            accx[ni] = __builtin_amdgcn_mfma_f32_16x16x32_f16(al, bh[ni], accx[ni], 0, 0, 0);
        }
        __builtin_amdgcn_s_setprio(0);

        A0a = A1a; A0b = A1b; A1a = A2a; A1b = A2b;
    }

    // drain DMA writes before reusing the LDS union for the epilogue
    asm volatile("s_waitcnt vmcnt(0)" ::: "memory");
    __syncthreads();

    // ---- fused epilogue ----
    #pragma unroll
    for (int ni = 0; ni < 4; ++ni) {
        const floatx4 v = acch[ni] + accx[ni] * (1.0f / 2048.0f);
        const int col = nt0 + ni * 16 + lr;
        #pragma unroll
        for (int reg = 0; reg < 4; ++reg)
            sm.e.Cs[mt0 + lg4 * 4 + reg][col] = v[reg];
    }
    __syncthreads();

    // per-row top-2: 8 threads/row, 8 experts each, shuffle merge
    {
        const int sr = t >> 3;          // row 0..31
        const int eg = (t & 7) * 8;     // expert base
        const int grow = rowBase + sr;
        const float* urow = noise_u + (size_t)grow * 64 + eg;
        const float4 u0 = *(const float4*)urow;
        const float4 u1 = *(const float4*)(urow + 4);
        const float uu[8] = {u0.x, u0.y, u0.z, u0.w, u1.x, u1.y, u1.z, u1.w};
        float v1 = -3.0e38f, v2 = -3.0e38f;
        int i1 = 0, i2 = 0;
        #pragma unroll
        for (int j = 0; j < 8; ++j) {
            const int e = eg + j;
            const float lg = sm.e.Cs[sr][e] + router_b[e];
            const float nz = sm.e.Cs[sr][64 + e] + noise_b[e];
            const float sp = fmaxf(nz, 0.0f) + log1pf(expf(-fabsf(nz)));
            const float nv = lg + sp * uu[j];
            if (nv > v1)      { v2 = v1; i2 = i1; v1 = nv; i1 = e; }
            else if (nv > v2) { v2 = nv; i2 = e; }
        }
        #pragma unroll
        for (int m = 1; m < 8; m <<= 1) {
            const float ov1 = __shfl_xor(v1, m, 64);
            const int   oi1 = __shfl_xor(i1, m, 64);
            const float ov2 = __shfl_xor(v2, m, 64);
            const int   oi2 = __shfl_xor(i2, m, 64);
            const bool takeO = (ov1 > v1) || (ov1 == v1 && oi1 < i1);
            const float t1v = takeO ? ov1 : v1;  const int t1i = takeO ? oi1 : i1;
            const float c2v = takeO ? v1 : ov1;  const int c2i = takeO ? i1 : oi1;
            const float c3v = takeO ? ov2 : v2;  const int c3i = takeO ? oi2 : i2;
            const bool k2 = (c3v > c2v) || (c3v == c2v && c3i < c2i);
            v1 = t1v; i1 = t1i;
            v2 = k2 ? c3v : c2v; i2 = k2 ? c3i : c2i;
        }
        if ((t & 7) == 0) {
            const float e2 = expf(v2 - v1);
            const float dn = 1.0f + e2;   // other 62 slots: exp(-1e30 - m) == 0
            sm.e.p1[sr] = 1.0f / dn;
            sm.e.p2[sr] = e2 / dn;
            sm.e.i1[sr] = i1;
            sm.e.i2[sr] = i2;
            float2 idx2;
            idx2.x = (float)i1;
            idx2.y = (float)i2;
            *(float2*)&out[(size_t)M_TOTAL * 64 + (size_t)grow * 2] = idx2;
        }
    }
    __syncthreads();

    // cooperative sparse-softmax write: 32 rows x 64 experts, 8 floats/thread
    {
        const int rr = t >> 3;
        const int e0 = (t & 7) * 8;
        const int g2 = rowBase + rr;
        const int j1 = sm.e.i1[rr], j2 = sm.e.i2[rr];
        const float q1 = sm.e.p1[rr], q2 = sm.e.p2[rr];
        float* orow = out + (size_t)g2 * 64;
        #pragma unroll
        for (int g = 0; g < 2; ++g) {
            const int b0i = e0 + g * 4;
            float4 v;
            v.x = (b0i + 0 == j1) ? q1 : (b0i + 0 == j2) ? q2 : 0.0f;
            v.y = (b0i + 1 == j1) ? q1 : (b0i + 1 == j2) ? q2 : 0.0f;
            v.z = (b0i + 2 == j1) ? q1 : (b0i + 2 == j2) ? q2 : 0.0f;
            v.w = (b0i + 3 == j1) ? q1 : (b0i + 3 == j2) ? q2 : 0.0f;
            *(float4*)&orow[b0i] = v;
        }
    }
}

extern "C" void kernel_launch(void* const* d_in, const int* in_sizes, int n_in,
                              void* d_out, int out_size, void* d_ws, size_t ws_size,
                              hipStream_t stream) {
    const float* x  = (const float*)d_in[0];
    const float* rw = (const float*)d_in[1];
    const float* rb = (const float*)d_in[2];
    const float* nw = (const float*)d_in[3];
    const float* nb = (const float*)d_in[4];
    const float* nu = (const float*)d_in[5];
    float* out = (float*)d_out;
    _Float16* wsB = (_Float16*)d_ws;
    (void)in_sizes; (void)n_in; (void)out_size; (void)ws_size;

    hipLaunchKernelGGL(conv_w_kernel, dim3(128), dim3(256), 0, stream, rw, nw, wsB);
    hipLaunchKernelGGL(gemm_router_kernel, dim3(M_TOTAL / BM), dim3(NT), 0, stream,
                       x, wsB, rb, nb, nu, out);
}

// Round 3
// 234.021 us; speedup vs baseline: 1.1328x; 1.1328x over previous
//
#include <hip/hip_runtime.h>
#include <math.h>

typedef __fp16   fp16x2  __attribute__((ext_vector_type(2)));
typedef _Float16 half8   __attribute__((ext_vector_type(8)));
typedef float    floatx4 __attribute__((ext_vector_type(4)));

#define M_TOTAL 16384
#define K_DIM   2048
#define NCOL    128
#define BM      32
#define BK      32
#define NT      256
#define NCHUNK  (K_DIM / BK)   // 64

// halves offsets within one LDS buffer
// layout: [Ahi 1024][Alo 1024][Bhi 4096][Blo 4096] halves = 20480 B
#define A_HI  0
#define A_LO  1024
#define B_HI  2048
#define B_LO  6144
#define BUF_H 10240

__device__ __forceinline__ void gl_lds16(const _Float16* g, _Float16* l) {
    __builtin_amdgcn_global_load_lds((const __attribute__((address_space(1))) void*)g,
                                     (__attribute__((address_space(3))) void*)l, 16, 0, 0);
}

__device__ __forceinline__ void cvt_store(const float4 v, _Float16* hiP, _Float16* loP) {
    fp16x2 h01 = __builtin_amdgcn_cvt_pkrtz(v.x, v.y);
    fp16x2 h23 = __builtin_amdgcn_cvt_pkrtz(v.z, v.w);
    float r0 = (v.x - (float)h01.x) * 2048.0f;
    float r1 = (v.y - (float)h01.y) * 2048.0f;
    float r2 = (v.z - (float)h23.x) * 2048.0f;
    float r3 = (v.w - (float)h23.y) * 2048.0f;
    fp16x2 l01 = __builtin_amdgcn_cvt_pkrtz(r0, r1);
    fp16x2 l23 = __builtin_amdgcn_cvt_pkrtz(r2, r3);
    union { fp16x2 h[2]; uint2 u; } ph, pl;
    ph.h[0] = h01; ph.h[1] = h23;
    pl.h[0] = l01; pl.h[1] = l23;
    *(uint2*)hiP = ph.u;
    *(uint2*)loP = pl.u;
}

// Pre-convert W (router||noise, fp32 [128][2048]) into ws as hi/lo f16,
// granule-major per 32-k chunk: chunk c = 8192 halves:
//   hi: [(g*128 + col)*8 + j]  (g=0..3 k-granule, col=0..127, j=0..7)
//   lo: same at +4096 halves
__global__ __launch_bounds__(256) void conv_w_kernel(
    const float* __restrict__ rw, const float* __restrict__ nw,
    _Float16* __restrict__ wsB)
{
    const int u   = blockIdx.x * 256 + threadIdx.x;  // 0..32767
    const int col = u & 127;
    const int g   = (u >> 7) & 3;
    const int c   = u >> 9;
    const float* srcRow = (col < 64) ? (rw + (size_t)col * K_DIM)
                                     : (nw + (size_t)(col - 64) * K_DIM);
    const float* src = srcRow + c * BK + g * 8;
    const float4 v0 = *(const float4*)src;
    const float4 v1 = *(const float4*)(src + 4);
    union { fp16x2 h[4]; uint4 q; } ph, pl;
    ph.h[0] = __builtin_amdgcn_cvt_pkrtz(v0.x, v0.y);
    ph.h[1] = __builtin_amdgcn_cvt_pkrtz(v0.z, v0.w);
    ph.h[2] = __builtin_amdgcn_cvt_pkrtz(v1.x, v1.y);
    ph.h[3] = __builtin_amdgcn_cvt_pkrtz(v1.z, v1.w);
    pl.h[0] = __builtin_amdgcn_cvt_pkrtz((v0.x - (float)ph.h[0].x) * 2048.0f,
                                         (v0.y - (float)ph.h[0].y) * 2048.0f);
    pl.h[1] = __builtin_amdgcn_cvt_pkrtz((v0.z - (float)ph.h[1].x) * 2048.0f,
                                         (v0.w - (float)ph.h[1].y) * 2048.0f);
    pl.h[2] = __builtin_amdgcn_cvt_pkrtz((v1.x - (float)ph.h[2].x) * 2048.0f,
                                         (v1.y - (float)ph.h[2].y) * 2048.0f);
    pl.h[3] = __builtin_amdgcn_cvt_pkrtz((v1.z - (float)ph.h[3].x) * 2048.0f,
                                         (v1.w - (float)ph.h[3].y) * 2048.0f);
    const size_t base = (size_t)c * 8192 + ((size_t)g * 128 + col) * 8;
    *(uint4*)&wsB[base]        = ph.q;
    *(uint4*)&wsB[base + 4096] = pl.q;
}

// r0 structure (shared coalesced staging, 1 barrier/chunk) with ONE change:
// the A (x) load is issued TWO chunks ahead and carried in a register for a
// full iteration before cvt_store. This removes the mid-iteration
// s_waitcnt vmcnt(0) the compiler had to emit in r0 (cvt_store consumed an
// x-load issued ~150 cycles earlier, behind 4 newer gl_lds ops -> full drain
// against ~900-cycle HBM latency, every chunk).
__global__ __launch_bounds__(NT, 2) void gemm_router_kernel(
    const float* __restrict__ x,
    const _Float16* __restrict__ wsB,
    const float* __restrict__ router_b,
    const float* __restrict__ noise_b,
    const float* __restrict__ noise_u,
    float* __restrict__ out)
{
    __shared__ __align__(16) union {
        _Float16 S[2 * BUF_H];
        struct { float Cs[32][132]; float p1[32]; float p2[32]; int i1[32]; int i2[32]; } e;
    } sm;

    const int t    = threadIdx.x;
    const int lane = t & 63;
    const int w    = t >> 6;
    const int rowBase = blockIdx.x * BM;

    // A staging map: thread -> (row r, k-quad q)  (fully coalesced)
    const int r = t >> 3, q = t & 7;
    const float* pa = x + (size_t)(rowBase + r) * K_DIM + q * 4;
    const int aw = ((q >> 1) * 32 + r) * 8 + (q & 1) * 4;  // halves, granule-major [g][row]

    // fragment map: wave w -> rows mt0..+16, cols nt0..+64
    const int lr  = lane & 15;
    const int lg4 = lane >> 4;
    const int mt0 = (w & 1) * 16;
    const int nt0 = (w >> 1) * 64;
    const int aOff = (lg4 * 32 + mt0 + lr) * 8;

    floatx4 acch[4], accx[4];
    #pragma unroll
    for (int ni = 0; ni < 4; ++ni) { acch[ni] = (floatx4)0.0f; accx[ni] = (floatx4)0.0f; }

    // prologue: stage B(0) + A(0); pre-load A(1) into the carry register
    {
        #pragma unroll
        for (int i = 0; i < 4; ++i) {
            const int n = w * 4 + i;
            gl_lds16(wsB + n * 512 + lane * 8, &sm.S[B_HI + n * 512]);
        }
    }
    float4 a0 = *(const float4*)pa;
    cvt_store(a0, &sm.S[A_HI + aw], &sm.S[A_LO + aw]);     // one-time stall
    float4 aCarry = *(const float4*)(pa + BK);             // A(1), in flight

    for (int c = 0; c < NCHUNK; ++c) {
        __syncthreads();  // drains: B(c) staged, A(c) staged, A(c+1) load done
        _Float16* buf  = sm.S + (c & 1) * BUF_H;
        _Float16* bufn = sm.S + ((c + 1) & 1) * BUF_H;

        // issue next-next A first (longest latency), then next B DMA
        float4 aNew = aCarry;
        if (c + 2 < NCHUNK)
            aNew = *(const float4*)(pa + (c + 2) * BK);
        if (c + 1 < NCHUNK) {
            const _Float16* wc = wsB + (size_t)(c + 1) * 8192;
            #pragma unroll
            for (int i = 0; i < 4; ++i) {
                const int n = w * 4 + i;
                gl_lds16(wc + n * 512 + lane * 8, bufn + B_HI + n * 512);
            }
        }

        const half8 ah = *(const half8*)&buf[A_HI + aOff];
        const half8 al = *(const half8*)&buf[A_LO + aOff];
        half8 bh[4], bl[4];
        #pragma unroll
        for (int ni = 0; ni < 4; ++ni) {
            const int bo = (lg4 * 128 + nt0 + ni * 16 + lr) * 8;
            bh[ni] = *(const half8*)&buf[B_HI + bo];
            bl[ni] = *(const half8*)&buf[B_LO + bo];
        }
        #pragma unroll
        for (int ni = 0; ni < 4; ++ni) {
            acch[ni] = __builtin_amdgcn_mfma_f32_16x16x32_f16(ah, bh[ni], acch[ni], 0, 0, 0);
            accx[ni] = __builtin_amdgcn_mfma_f32_16x16x32_f16(ah, bl[ni], accx[ni], 0, 0, 0);
            accx[ni] = __builtin_amdgcn_mfma_f32_16x16x32_f16(al, bh[ni], accx[ni], 0, 0, 0);
        }

        // store A(c+1): loaded one full iteration ago, already complete ->
        // no vmcnt(0) drain here (this-iteration loads stay in flight)
        if (c + 1 < NCHUNK)
            cvt_store(aCarry, &bufn[A_HI + aw], &bufn[A_LO + aw]);
        aCarry = aNew;
    }

    // ---- fused epilogue ----
    // chunk 63 used buf1 (halves 10240..); Cs occupies halves 0..8448 -> no race
    #pragma unroll
    for (int ni = 0; ni < 4; ++ni) {
        const floatx4 v = acch[ni] + accx[ni] * (1.0f / 2048.0f);
        const int col = nt0 + ni * 16 + lr;
        #pragma unroll
        for (int reg = 0; reg < 4; ++reg)
            sm.e.Cs[mt0 + lg4 * 4 + reg][col] = v[reg];
    }
    __syncthreads();

    // per-row top-2: 8 threads/row, 8 experts each, shuffle merge
    {
        const int sr = t >> 3;          // row 0..31
        const int eg = (t & 7) * 8;     // expert base
        const int grow = rowBase + sr;
        const float* urow = noise_u + (size_t)grow * 64 + eg;
        const float4 u0 = *(const float4*)urow;
        const float4 u1 = *(const float4*)(urow + 4);
        const float uu[8] = {u0.x, u0.y, u0.z, u0.w, u1.x, u1.y, u1.z, u1.w};
        float v1 = -3.0e38f, v2 = -3.0e38f;
        int i1 = 0, i2 = 0;
        #pragma unroll
        for (int j = 0; j < 8; ++j) {
            const int e = eg + j;
            const float lg = sm.e.Cs[sr][e] + router_b[e];
            const float nz = sm.e.Cs[sr][64 + e] + noise_b[e];
            const float sp = fmaxf(nz, 0.0f) + log1pf(expf(-fabsf(nz)));
            const float nv = lg + sp * uu[j];
            if (nv > v1)      { v2 = v1; i2 = i1; v1 = nv; i1 = e; }
            else if (nv > v2) { v2 = nv; i2 = e; }
        }
        #pragma unroll
        for (int m = 1; m < 8; m <<= 1) {
            const float ov1 = __shfl_xor(v1, m, 64);
            const int   oi1 = __shfl_xor(i1, m, 64);
            const float ov2 = __shfl_xor(v2, m, 64);
            const int   oi2 = __shfl_xor(i2, m, 64);
            const bool takeO = (ov1 > v1) || (ov1 == v1 && oi1 < i1);
            const float t1v = takeO ? ov1 : v1;  const int t1i = takeO ? oi1 : i1;
            const float c2v = takeO ? v1 : ov1;  const int c2i = takeO ? i1 : oi1;
            const float c3v = takeO ? ov2 : v2;  const int c3i = takeO ? oi2 : i2;
            const bool k2 = (c3v > c2v) || (c3v == c2v && c3i < c2i);
            v1 = t1v; i1 = t1i;
            v2 = k2 ? c3v : c2v; i2 = k2 ? c3i : c2i;
        }
        if ((t & 7) == 0) {
            const float e2 = expf(v2 - v1);
            const float dn = 1.0f + e2;   // other 62 slots: exp(-1e30 - m) == 0
            sm.e.p1[sr] = 1.0f / dn;
            sm.e.p2[sr] = e2 / dn;
            sm.e.i1[sr] = i1;
            sm.e.i2[sr] = i2;
            float2 idx2;
            idx2.x = (float)i1;
            idx2.y = (float)i2;
            *(float2*)&out[(size_t)M_TOTAL * 64 + (size_t)grow * 2] = idx2;
        }
    }
    __syncthreads();

    // cooperative sparse-softmax write: 32 rows x 64 experts, 8 floats/thread
    {
        const int rr = t >> 3;
        const int e0 = (t & 7) * 8;
        const int g2 = rowBase + rr;
        const int j1 = sm.e.i1[rr], j2 = sm.e.i2[rr];
        const float q1 = sm.e.p1[rr], q2 = sm.e.p2[rr];
        float* orow = out + (size_t)g2 * 64;
        #pragma unroll
        for (int g = 0; g < 2; ++g) {
            const int b0 = e0 + g * 4;
            float4 v;
            v.x = (b0 + 0 == j1) ? q1 : (b0 + 0 == j2) ? q2 : 0.0f;
            v.y = (b0 + 1 == j1) ? q1 : (b0 + 1 == j2) ? q2 : 0.0f;
            v.z = (b0 + 2 == j1) ? q1 : (b0 + 2 == j2) ? q2 : 0.0f;
            v.w = (b0 + 3 == j1) ? q1 : (b0 + 3 == j2) ? q2 : 0.0f;
            *(float4*)&orow[b0] = v;
        }
    }
}

extern "C" void kernel_launch(void* const* d_in, const int* in_sizes, int n_in,
                              void* d_out, int out_size, void* d_ws, size_t ws_size,
                              hipStream_t stream) {
    const float* x  = (const float*)d_in[0];
    const float* rw = (const float*)d_in[1];
    const float* rb = (const float*)d_in[2];
    const float* nw = (const float*)d_in[3];
    const float* nb = (const float*)d_in[4];
    const float* nu = (const float*)d_in[5];
    float* out = (float*)d_out;
    _Float16* wsB = (_Float16*)d_ws;
    (void)in_sizes; (void)n_in; (void)out_size; (void)ws_size;

    hipLaunchKernelGGL(conv_w_kernel, dim3(128), dim3(256), 0, stream, rw, nw, wsB);
    hipLaunchKernelGGL(gemm_router_kernel, dim3(M_TOTAL / BM), dim3(NT), 0, stream,
                       x, wsB, rb, nb, nu, out);
}

// Round 4
// 230.939 us; speedup vs baseline: 1.1479x; 1.0133x over previous
//
#include <hip/hip_runtime.h>
#include <math.h>

typedef __fp16   fp16x2  __attribute__((ext_vector_type(2)));
typedef _Float16 half8   __attribute__((ext_vector_type(8)));
typedef float    floatx4 __attribute__((ext_vector_type(4)));

#define M_TOTAL 16384
#define K_DIM   2048
#define NCOL    128
#define BM      32
#define BK      32
#define NT      256
#define NCHUNK  (K_DIM / BK)   // 64

// halves offsets within one LDS buffer
// layout: [Ahi 1024][Alo 1024][Bhi 4096][Blo 4096] halves = 20480 B
#define A_HI  0
#define A_LO  1024
#define B_HI  2048
#define B_LO  6144
#define BUF_H 10240

__device__ __forceinline__ void gl_lds16(const _Float16* g, _Float16* l) {
    __builtin_amdgcn_global_load_lds((const __attribute__((address_space(1))) void*)g,
                                     (__attribute__((address_space(3))) void*)l, 16, 0, 0);
}

__device__ __forceinline__ void cvt_store(const float4 v, _Float16* hiP, _Float16* loP) {
    fp16x2 h01 = __builtin_amdgcn_cvt_pkrtz(v.x, v.y);
    fp16x2 h23 = __builtin_amdgcn_cvt_pkrtz(v.z, v.w);
    float r0 = (v.x - (float)h01.x) * 2048.0f;
    float r1 = (v.y - (float)h01.y) * 2048.0f;
    float r2 = (v.z - (float)h23.x) * 2048.0f;
    float r3 = (v.w - (float)h23.y) * 2048.0f;
    fp16x2 l01 = __builtin_amdgcn_cvt_pkrtz(r0, r1);
    fp16x2 l23 = __builtin_amdgcn_cvt_pkrtz(r2, r3);
    union { fp16x2 h[2]; uint2 u; } ph, pl;
    ph.h[0] = h01; ph.h[1] = h23;
    pl.h[0] = l01; pl.h[1] = l23;
    *(uint2*)hiP = ph.u;
    *(uint2*)loP = pl.u;
}

// Pre-convert W (router||noise, fp32 [128][2048]) into ws as hi/lo f16,
// granule-major per 32-k chunk: chunk c = 8192 halves:
//   hi: [(g*128 + col)*8 + j]  (g=0..3 k-granule, col=0..127, j=0..7)
//   lo: same at +4096 halves
__global__ __launch_bounds__(256) void conv_w_kernel(
    const float* __restrict__ rw, const float* __restrict__ nw,
    _Float16* __restrict__ wsB)
{
    const int u   = blockIdx.x * 256 + threadIdx.x;  // 0..32767
    const int col = u & 127;
    const int g   = (u >> 7) & 3;
    const int c   = u >> 9;
    const float* srcRow = (col < 64) ? (rw + (size_t)col * K_DIM)
                                     : (nw + (size_t)(col - 64) * K_DIM);
    const float* src = srcRow + c * BK + g * 8;
    const float4 v0 = *(const float4*)src;
    const float4 v1 = *(const float4*)(src + 4);
    union { fp16x2 h[4]; uint4 q; } ph, pl;
    ph.h[0] = __builtin_amdgcn_cvt_pkrtz(v0.x, v0.y);
    ph.h[1] = __builtin_amdgcn_cvt_pkrtz(v0.z, v0.w);
    ph.h[2] = __builtin_amdgcn_cvt_pkrtz(v1.x, v1.y);
    ph.h[3] = __builtin_amdgcn_cvt_pkrtz(v1.z, v1.w);
    pl.h[0] = __builtin_amdgcn_cvt_pkrtz((v0.x - (float)ph.h[0].x) * 2048.0f,
                                         (v0.y - (float)ph.h[0].y) * 2048.0f);
    pl.h[1] = __builtin_amdgcn_cvt_pkrtz((v0.z - (float)ph.h[1].x) * 2048.0f,
                                         (v0.w - (float)ph.h[1].y) * 2048.0f);
    pl.h[2] = __builtin_amdgcn_cvt_pkrtz((v1.x - (float)ph.h[2].x) * 2048.0f,
                                         (v1.y - (float)ph.h[2].y) * 2048.0f);
    pl.h[3] = __builtin_amdgcn_cvt_pkrtz((v1.z - (float)ph.h[3].x) * 2048.0f,
                                         (v1.w - (float)ph.h[3].y) * 2048.0f);
    const size_t base = (size_t)c * 8192 + ((size_t)g * 128 + col) * 8;
    *(uint4*)&wsB[base]        = ph.q;
    *(uint4*)&wsB[base + 4096] = pl.q;
}

// Triple-buffered K-loop with raw s_barrier + counted vmcnt (T3/T4):
// each body issues EXACTLY 5 vmem ops (1 x-load + 4 gl_lds), so
// s_waitcnt vmcnt(5) at body top drains exactly the group issued 2 bodies
// ago (B(c) staged, A(c+2) register valid) while the newest 5 stay in
// flight ACROSS the barrier. No vmcnt(0) drain anywhere in the loop.
// body(c): read buf[c%3], write buf[(c+2)%3] (== buffer read at c-1 --
// all waves finished reading it before barrier(c), so no race).
__global__ __launch_bounds__(NT, 2) void gemm_router_kernel(
    const float* __restrict__ x,
    const _Float16* __restrict__ wsB,
    const float* __restrict__ router_b,
    const float* __restrict__ noise_b,
    const float* __restrict__ noise_u,
    float* __restrict__ out)
{
    __shared__ __align__(16) union {
        _Float16 S[3 * BUF_H];   // 61440 B
        struct { float Cs[32][132]; float p1[32]; float p2[32]; int i1[32]; int i2[32]; } e;
    } sm;

    const int t    = threadIdx.x;
    const int lane = t & 63;
    const int w    = t >> 6;
    const int rowBase = blockIdx.x * BM;

    // A staging map: thread -> (row r, k-quad q)  (fully coalesced)
    const int r = t >> 3, q = t & 7;
    const float* pa = x + (size_t)(rowBase + r) * K_DIM + q * 4;
    const int aw = ((q >> 1) * 32 + r) * 8 + (q & 1) * 4;  // halves, granule-major [g][row]

    // fragment map: wave w -> rows mt0..+16, cols nt0..+64
    const int lr  = lane & 15;
    const int lg4 = lane >> 4;
    const int mt0 = (w & 1) * 16;
    const int nt0 = (w >> 1) * 64;
    const int aOff = (lg4 * 32 + mt0 + lr) * 8;

    floatx4 acch[4], accx[4];
    #pragma unroll
    for (int ni = 0; ni < 4; ++ni) { acch[ni] = (floatx4)0.0f; accx[ni] = (floatx4)0.0f; }

    _Float16* p0 = sm.S;                // read buffer for current body
    _Float16* p1 = sm.S + BUF_H;
    _Float16* p2 = sm.S + 2 * BUF_H;    // write target (== buffer read last body)

    // ---- prologue: fenced issue groups so vmcnt counts are exact ----
    // group P0: A(0), A(1) plain loads (oldest -> drained by vmcnt(10))
    float4 a0v = *(const float4*)pa;
    float4 a1v = *(const float4*)(pa + BK);
    asm volatile("" ::: "memory");
    // group G(-2): A(2) + B(0) gl_lds x4 -> buf0
    float4 aS = *(const float4*)(pa + 2 * BK);
    #pragma unroll
    for (int i = 0; i < 4; ++i) {
        const int n = w * 4 + i;
        gl_lds16(wsB + n * 512 + lane * 8, p0 + B_HI + n * 512);
    }
    asm volatile("" ::: "memory");
    // group G(-1): A(3) + B(1) gl_lds x4 -> buf1
    float4 aN = *(const float4*)(pa + 3 * BK);
    #pragma unroll
    for (int i = 0; i < 4; ++i) {
        const int n = w * 4 + i;
        gl_lds16(wsB + 8192 + n * 512 + lane * 8, p1 + B_HI + n * 512);
    }
    asm volatile("" ::: "memory");
    asm volatile("s_waitcnt vmcnt(10)" ::: "memory");   // A(0),A(1) done
    cvt_store(a0v, &p0[A_HI + aw], &p0[A_LO + aw]);
    cvt_store(a1v, &p1[A_HI + aw], &p1[A_LO + aw]);
    asm volatile("s_waitcnt lgkmcnt(0)" ::: "memory");  // publish A stores

    for (int c = 0; c < NCHUNK; ++c) {
        // drain exactly the group issued 2 bodies ago: B(c)x4 staged + A(c+2) reg
        asm volatile("s_waitcnt vmcnt(5)" ::: "memory");
        asm volatile("s_barrier" ::: "memory");

        // issue this body's group early: A(c+4) + B(c+2)x4 -> p2
        const int cn2 = (c + 2 < NCHUNK) ? c + 2 : NCHUNK - 1;
        const int cn4 = (c + 4 < NCHUNK) ? c + 4 : NCHUNK - 1;
        float4 aNew = *(const float4*)(pa + cn4 * BK);
        {
            const _Float16* wc = wsB + (size_t)cn2 * 8192;
            #pragma unroll
            for (int i = 0; i < 4; ++i) {
                const int n = w * 4 + i;
                gl_lds16(wc + n * 512 + lane * 8, p2 + B_HI + n * 512);
            }
        }

        const half8 ah = *(const half8*)&p0[A_HI + aOff];
        const half8 al = *(const half8*)&p0[A_LO + aOff];
        half8 bh[4], bl[4];
        #pragma unroll
        for (int ni = 0; ni < 4; ++ni) {
            const int bo = (lg4 * 128 + nt0 + ni * 16 + lr) * 8;
            bh[ni] = *(const half8*)&p0[B_HI + bo];
            bl[ni] = *(const half8*)&p0[B_LO + bo];
        }

        __builtin_amdgcn_s_setprio(1);
        #pragma unroll
        for (int ni = 0; ni < 4; ++ni) {
            acch[ni] = __builtin_amdgcn_mfma_f32_16x16x32_f16(ah, bh[ni], acch[ni], 0, 0, 0);
            accx[ni] = __builtin_amdgcn_mfma_f32_16x16x32_f16(ah, bl[ni], accx[ni], 0, 0, 0);
            accx[ni] = __builtin_amdgcn_mfma_f32_16x16x32_f16(al, bh[ni], accx[ni], 0, 0, 0);
        }
        __builtin_amdgcn_s_setprio(0);

        // stage A(c+2) into p2 (register drained by this body's vmcnt(5))
        cvt_store(aS, &p2[A_HI + aw], &p2[A_LO + aw]);
        aS = aN; aN = aNew;

        // rotate buffers: next body reads p1, writes p0
        _Float16* tmp = p0; p0 = p1; p1 = p2; p2 = tmp;
    }

    // drain dangling DMA (targets buf1/buf2 only -- no Cs overlap, but be safe),
    // and make sure no wave is still ds_reading buf0 (chunk 63 read buf0, which
    // the epilogue union overlaps) before Cs writes begin.
    asm volatile("s_waitcnt vmcnt(0)" ::: "memory");
    __syncthreads();

    // ---- fused epilogue ----
    #pragma unroll
    for (int ni = 0; ni < 4; ++ni) {
        const floatx4 v = acch[ni] + accx[ni] * (1.0f / 2048.0f);
        const int col = nt0 + ni * 16 + lr;
        #pragma unroll
        for (int reg = 0; reg < 4; ++reg)
            sm.e.Cs[mt0 + lg4 * 4 + reg][col] = v[reg];
    }
    __syncthreads();

    // per-row top-2: 8 threads/row, 8 experts each, shuffle merge
    {
        const int sr = t >> 3;          // row 0..31
        const int eg = (t & 7) * 8;     // expert base
        const int grow = rowBase + sr;
        const float* urow = noise_u + (size_t)grow * 64 + eg;
        const float4 u0 = *(const float4*)urow;
        const float4 u1 = *(const float4*)(urow + 4);
        const float uu[8] = {u0.x, u0.y, u0.z, u0.w, u1.x, u1.y, u1.z, u1.w};
        float v1 = -3.0e38f, v2 = -3.0e38f;
        int i1 = 0, i2 = 0;
        #pragma unroll
        for (int j = 0; j < 8; ++j) {
            const int e = eg + j;
            const float lg = sm.e.Cs[sr][e] + router_b[e];
            const float nz = sm.e.Cs[sr][64 + e] + noise_b[e];
            const float sp = fmaxf(nz, 0.0f) + log1pf(expf(-fabsf(nz)));
            const float nv = lg + sp * uu[j];
            if (nv > v1)      { v2 = v1; i2 = i1; v1 = nv; i1 = e; }
            else if (nv > v2) { v2 = nv; i2 = e; }
        }
        #pragma unroll
        for (int m = 1; m < 8; m <<= 1) {
            const float ov1 = __shfl_xor(v1, m, 64);
            const int   oi1 = __shfl_xor(i1, m, 64);
            const float ov2 = __shfl_xor(v2, m, 64);
            const int   oi2 = __shfl_xor(i2, m, 64);
            const bool takeO = (ov1 > v1) || (ov1 == v1 && oi1 < i1);
            const float t1v = takeO ? ov1 : v1;  const int t1i = takeO ? oi1 : i1;
            const float c2v = takeO ? v1 : ov1;  const int c2i = takeO ? i1 : oi1;
            const float c3v = takeO ? ov2 : v2;  const int c3i = takeO ? oi2 : i2;
            const bool k2 = (c3v > c2v) || (c3v == c2v && c3i < c2i);
            v1 = t1v; i1 = t1i;
            v2 = k2 ? c3v : c2v; i2 = k2 ? c3i : c2i;
        }
        if ((t & 7) == 0) {
            const float e2 = expf(v2 - v1);
            const float dn = 1.0f + e2;   // other 62 slots: exp(-1e30 - m) == 0
            sm.e.p1[sr] = 1.0f / dn;
            sm.e.p2[sr] = e2 / dn;
            sm.e.i1[sr] = i1;
            sm.e.i2[sr] = i2;
            float2 idx2;
            idx2.x = (float)i1;
            idx2.y = (float)i2;
            *(float2*)&out[(size_t)M_TOTAL * 64 + (size_t)grow * 2] = idx2;
        }
    }
    __syncthreads();

    // cooperative sparse-softmax write: 32 rows x 64 experts, 8 floats/thread
    {
        const int rr = t >> 3;
        const int e0 = (t & 7) * 8;
        const int g2 = rowBase + rr;
        const int j1 = sm.e.i1[rr], j2 = sm.e.i2[rr];
        const float q1 = sm.e.p1[rr], q2 = sm.e.p2[rr];
        float* orow = out + (size_t)g2 * 64;
        #pragma unroll
        for (int g = 0; g < 2; ++g) {
            const int b0 = e0 + g * 4;
            float4 v;
            v.x = (b0 + 0 == j1) ? q1 : (b0 + 0 == j2) ? q2 : 0.0f;
            v.y = (b0 + 1 == j1) ? q1 : (b0 + 1 == j2) ? q2 : 0.0f;
            v.z = (b0 + 2 == j1) ? q1 : (b0 + 2 == j2) ? q2 : 0.0f;
            v.w = (b0 + 3 == j1) ? q1 : (b0 + 3 == j2) ? q2 : 0.0f;
            *(float4*)&orow[b0] = v;
        }
    }
}

extern "C" void kernel_launch(void* const* d_in, const int* in_sizes, int n_in,
                              void* d_out, int out_size, void* d_ws, size_t ws_size,
                              hipStream_t stream) {
    const float* x  = (const float*)d_in[0];
    const float* rw = (const float*)d_in[1];
    const float* rb = (const float*)d_in[2];
    const float* nw = (const float*)d_in[3];
    const float* nb = (const float*)d_in[4];
    const float* nu = (const float*)d_in[5];
    float* out = (float*)d_out;
    _Float16* wsB = (_Float16*)d_ws;
    (void)in_sizes; (void)n_in; (void)out_size; (void)ws_size;

    hipLaunchKernelGGL(conv_w_kernel, dim3(128), dim3(256), 0, stream, rw, nw, wsB);
    hipLaunchKernelGGL(gemm_router_kernel, dim3(M_TOTAL / BM), dim3(NT), 0, stream,
                       x, wsB, rb, nb, nu, out);
}